// Round 8
// baseline (222.530 us; speedup 1.0000x reference)
//
#include <hip/hip_runtime.h>
#include <math.h>

// Problem constants
#define HH 2048
#define EE 64
#define TOPK 8
#define NT 16384
#define MT 64            // tokens per WG (2 tg groups of 32)
#define KC 64            // K elems per chunk (4 k-steps)
#define NCH 32           // HH / KC
#define LS 68            // slog row stride (floats)

typedef __attribute__((ext_vector_type(8)))  short short8;  // 8 bf16 (4 VGPRs)
typedef __attribute__((ext_vector_type(16))) float f32x16;  // 32x32 MFMA acc

// 3-limb bf16 split: v = h + m + l + eps, |eps| <= 2^-25 |v|.
// (identical to the rounds-3..7 harness-passing version)
static __device__ __forceinline__ void cvt3(const float4& a, const float4& b,
                                            short8& h, short8& m, short8& l)
{
    const float v[8] = {a.x, a.y, a.z, a.w, b.x, b.y, b.z, b.w};
#pragma unroll
    for (int i = 0; i < 8; ++i) {
        const unsigned int u = __float_as_uint(v[i]);
        h[i] = (short)(u >> 16);
        const float r1 = v[i] - __uint_as_float(u & 0xffff0000u);
        const unsigned int u1 = __float_as_uint(r1);
        m[i] = (short)(u1 >> 16);
        const float r2 = r1 - __uint_as_float(u1 & 0xffff0000u);
        const unsigned int u2 = __float_as_uint(r2);
        l[i] = (short)((u2 + 0x7fffu + ((u2 >> 16) & 1u)) >> 16);
    }
}

// ---------------- Pre-kernel: W -> fragment-ready 3-limb bf16 ----------------
// Layout: [eb][s16][limb p][lane][8 shorts], s16 = global 16-k-step (0..127),
// lane = l5*32 + (e&31) = exact MFMA B-fragment order. Main-kernel B load =
// 3 fully-coalesced 1KB dwordx4 loads per k-step. Total 768 KB, L2-resident.
// (identical to the rounds-5/7 harness-passing version)
__global__ __launch_bounds__(256) void wsplit(
    const float* __restrict__ w, short* __restrict__ wsw)
{
    const int e = blockIdx.x;        // expert 0..63
    const int o = threadIdx.x;       // k-octet 0..255
    const int k = o * 8;
    const float4 a = *(const float4*)(w + (size_t)e * HH + k);
    const float4 b = *(const float4*)(w + (size_t)e * HH + k + 4);
    short8 h, m, l;
    cvt3(a, b, h, m, l);

    const int eb  = e >> 5, lr = e & 31;
    const int s16 = o >> 1;          // 16-k-step index
    const int l5  = o & 1;           // k-octet within step
    const int lane = l5 * 32 + lr;
    short* dst = wsw + (((size_t)(eb * 128 + s16) * 3) * 64 + lane) * 8;
    *(short8*)(dst)           = h;   // p=0
    *(short8*)(dst + 64 * 8)  = m;   // p=1
    *(short8*)(dst + 128 * 8) = l;   // p=2
}

// ---------------- Main kernel ----------------
// 1024 threads = 16 waves = eb(2) x kq(4) x tg(2); 64 tokens/block, grid 256.
// Each block reads W ONCE for 64 tokens (halves the dominant W-limb traffic
// vs MT=32). Staging threads (t<512) read x coalesced, cvt3 once, write
// fragment-ready limb tiles to 48 KB double-buffered LDS. Compute inner loop:
// 3 coalesced L2 B-loads + 3 ds_read_b128 + 6 MFMA per wave per chunk.
__global__ __launch_bounds__(1024, 4) void router_fused(
    const float* __restrict__ x,          // [NT, H] fp32
    const short* __restrict__ wsw,        // fragment-ready W limbs
    float* __restrict__ out_logits,
    float* __restrict__ out_wts,
    float* __restrict__ out_idx)
{
    // [buf][ ((s16l*3+p)*2+tg)*64 + swizzled lane ] short8 units; 48 KB total
    __shared__ __align__(16) short8 xsl[2][1536];
    float* slog = (float*)xsl;            // epilogue overlay (17.4 KB)

    const int t    = threadIdx.x;
    const int wv   = t >> 6;
    const int lane = t & 63;
    const int eb   = wv & 1;              // expert half (32 cols)
    const int kq   = (wv >> 1) & 3;       // k-step slot within chunk (stride-4 K partition)
    const int tg   = wv >> 3;             // token group of 32
    const int l5   = lane >> 5;           // k-octet within 16-k step
    const int lr   = lane & 31;           // token row (A) / expert col (B)
    const int tok0 = blockIdx.x * MT;

    // staging role (t < 512): thread owns (row sr, k-octet su) of 64x64 tile
    const int sr  = t >> 3;               // 0..63
    const int su  = t & 7;                // octet 0..7
    const float* xg = x + (size_t)(tok0 + sr) * HH + su * 8;
    const int s16s = su >> 1;             // k-step within chunk
    const int tgs  = sr >> 5;             // token group this row feeds
    const int lfs  = (su & 1) * 32 + (sr & 31);   // fragment lane

    f32x16 accM = {0}, accS = {0};
    float4 xr0, xr1;

    auto sload = [&](int c) {
        xr0 = *(const float4*)(xg + (size_t)c * KC);
        xr1 = *(const float4*)(xg + (size_t)c * KC + 4);
    };
    auto swrite = [&](int buf) {
        short8 h, m, l;
        cvt3(xr0, xr1, h, m, l);
        const int b0 = (s16s * 3 + 0) * 2 + tgs;
        const int b1 = (s16s * 3 + 1) * 2 + tgs;
        const int b2 = (s16s * 3 + 2) * 2 + tgs;
        xsl[buf][(b0 << 6) + (lfs ^ (b0 & 7))] = h;
        xsl[buf][(b1 << 6) + (lfs ^ (b1 & 7))] = m;
        xsl[buf][(b2 << 6) + (lfs ^ (b2 & 7))] = l;
    };
    auto chunk = [&](int c, int buf) {
        const int s16g = c * 4 + kq;      // global k-step this wave handles
        const short8* wp = (const short8*)wsw
                         + ((size_t)(eb * 128 + s16g) * 3) * 64 + lane;
        const short8 B0 = wp[0];
        const short8 B1 = wp[64];
        const short8 B2 = wp[128];
        const int a0 = (kq * 3 + 0) * 2 + tg;
        const int a1 = (kq * 3 + 1) * 2 + tg;
        const int a2 = (kq * 3 + 2) * 2 + tg;
        const short8 Ah = xsl[buf][(a0 << 6) + (lane ^ (a0 & 7))];
        const short8 Am = xsl[buf][(a1 << 6) + (lane ^ (a1 & 7))];
        const short8 Al = xsl[buf][(a2 << 6) + (lane ^ (a2 & 7))];
        accM = __builtin_amdgcn_mfma_f32_32x32x16_bf16(Ah, B0, accM, 0, 0, 0);
        accS = __builtin_amdgcn_mfma_f32_32x32x16_bf16(Ah, B1, accS, 0, 0, 0);
        accS = __builtin_amdgcn_mfma_f32_32x32x16_bf16(Am, B0, accS, 0, 0, 0);
        accS = __builtin_amdgcn_mfma_f32_32x32x16_bf16(Ah, B2, accS, 0, 0, 0);
        accS = __builtin_amdgcn_mfma_f32_32x32x16_bf16(Al, B0, accS, 0, 0, 0);
        accS = __builtin_amdgcn_mfma_f32_32x32x16_bf16(Am, B1, accS, 0, 0, 0);
    };

    // prologue: stage chunk 0
    if (t < 512) { sload(0); swrite(0); }
    __syncthreads();

#pragma unroll 1
    for (int c = 0; c < NCH; ++c) {
        if (t < 512 && c + 1 < NCH) sload(c + 1);   // issue next burst early
        chunk(c, c & 1);
        if (t < 512 && c + 1 < NCH) swrite((c + 1) & 1);
        __syncthreads();
    }
    // final barrier also guards the slog overlay below

    // ---- K-slot reduction into slog ----
    // 32x32 C/D layout (m74/m101): col = lane&31, row = (r&3)+8*(r>>2)+4*(l>>5)
    const int col = eb * 32 + lr;
#pragma unroll 1
    for (int q = 0; q < 4; ++q) {
        if (kq == q) {
#pragma unroll
            for (int r = 0; r < 16; ++r) {
                const int row = tg * 32 + (r & 3) + 8 * (r >> 2) + 4 * l5;
                const float val = accM[r] + accS[r];
                if (q == 0) slog[row * LS + col] = val;
                else        slog[row * LS + col] += val;
            }
        }
        __syncthreads();
    }

    // ---- coalesced logits write: 64 tokens x 64 experts, 1024 threads ----
    {
        const int row = t >> 4;           // 0..63
        const int c4  = (t & 15) * 4;
        const float4 o0 = *(const float4*)&slog[row * LS + c4];
        *(float4*)(out_logits + (size_t)(tok0 + row) * EE + c4) = o0;
    }

    // ---- top-8 + softmax: one lane per token (harness-proven code) ----
    if (t < MT) {
        float tv[TOPK];
        int   ti[TOPK];
#pragma unroll
        for (int q = 0; q < TOPK; ++q) { tv[q] = -INFINITY; ti[q] = 0; }

        for (int e = 0; e < EE; ++e) {
            const float val = slog[t * LS + e];
            if (val > tv[TOPK - 1]) {
                tv[TOPK - 1] = val;
                ti[TOPK - 1] = e;
#pragma unroll
                for (int q = TOPK - 1; q > 0; --q) {
                    if (tv[q] > tv[q - 1]) {   // strict: lowest-index-first on ties
                        float fv = tv[q]; tv[q] = tv[q - 1]; tv[q - 1] = fv;
                        int   fi = ti[q]; ti[q] = ti[q - 1]; ti[q - 1] = fi;
                    }
                }
            }
        }

        const float m = tv[0];
        float ew[TOPK];
        float sum = 0.f;
#pragma unroll
        for (int q = 0; q < TOPK; ++q) { ew[q] = expf(tv[q] - m); sum += ew[q]; }
        const float inv = 1.f / sum;

        const size_t tok = (size_t)(tok0 + t);
        float4 w0, w1, i0, i1;
        w0.x = ew[0] * inv; w0.y = ew[1] * inv; w0.z = ew[2] * inv; w0.w = ew[3] * inv;
        w1.x = ew[4] * inv; w1.y = ew[5] * inv; w1.z = ew[6] * inv; w1.w = ew[7] * inv;
        i0.x = (float)ti[0]; i0.y = (float)ti[1]; i0.z = (float)ti[2]; i0.w = (float)ti[3];
        i1.x = (float)ti[4]; i1.y = (float)ti[5]; i1.z = (float)ti[6]; i1.w = (float)ti[7];
        *(float4*)(out_wts + tok * TOPK)     = w0;
        *(float4*)(out_wts + tok * TOPK + 4) = w1;
        *(float4*)(out_idx + tok * TOPK)     = i0;
        *(float4*)(out_idx + tok * TOPK + 4) = i1;
    }
}

extern "C" void kernel_launch(void* const* d_in, const int* in_sizes, int n_in,
                              void* d_out, int out_size, void* d_ws, size_t ws_size,
                              hipStream_t stream) {
    const float* x = (const float*)d_in[0];   // hidden_states [4,4096,2048] fp32
    const float* w = (const float*)d_in[1];   // gate_w [64,2048] fp32
    float* out        = (float*)d_out;
    float* out_logits = out;                               // 16384*64
    float* out_wts    = out + (size_t)NT * EE;             // 16384*8
    float* out_idx    = out_wts + (size_t)NT * TOPK;       // 16384*8
    short* wsw = (short*)d_ws;                             // 768 KB limb planes

    hipLaunchKernelGGL(wsplit, dim3(EE), dim3(256), 0, stream, w, wsw);
    hipLaunchKernelGGL(router_fused, dim3(NT / MT), dim3(1024), 0, stream,
                       x, wsw, out_logits, out_wts, out_idx);
}

// Round 9
// 215.272 us; speedup vs baseline: 1.0337x; 1.0337x over previous
//
#include <hip/hip_runtime.h>
#include <math.h>

// Problem constants
#define HH 2048
#define EE 64
#define TOPK 8
#define NT 16384
#define MT 32            // tokens per WG
#define KC 128           // K elems per chunk (tile: 32 tokens x 128 k fp32)
#define NCH 16           // HH / KC
#define LS 68            // slog row stride (floats)

typedef __attribute__((ext_vector_type(8)))  short short8;  // 8 bf16 (4 VGPRs)
typedef __attribute__((ext_vector_type(16))) float f32x16;  // 32x32 MFMA acc

#define GLB(p) ((const __attribute__((address_space(1))) void*)(p))
#define LDS(p) ((__attribute__((address_space(3))) void*)(p))

// 3-limb bf16 split: v = h + m + l + eps, |eps| <= 2^-25 |v|.
// (identical to the rounds-3..8 harness-passing version)
static __device__ __forceinline__ void cvt3(const float4& a, const float4& b,
                                            short8& h, short8& m, short8& l)
{
    const float v[8] = {a.x, a.y, a.z, a.w, b.x, b.y, b.z, b.w};
#pragma unroll
    for (int i = 0; i < 8; ++i) {
        const unsigned int u = __float_as_uint(v[i]);
        h[i] = (short)(u >> 16);
        const float r1 = v[i] - __uint_as_float(u & 0xffff0000u);
        const unsigned int u1 = __float_as_uint(r1);
        m[i] = (short)(u1 >> 16);
        const float r2 = r1 - __uint_as_float(u1 & 0xffff0000u);
        const unsigned int u2 = __float_as_uint(r2);
        l[i] = (short)((u2 + 0x7fffu + ((u2 >> 16) & 1u)) >> 16);
    }
}

// ---------------- Pre-kernel: W -> fragment-ready 3-limb bf16 ----------------
// (identical to the rounds-5/7/8 harness-passing version)
__global__ __launch_bounds__(256) void wsplit(
    const float* __restrict__ w, short* __restrict__ wsw)
{
    const int e = blockIdx.x;        // expert 0..63
    const int o = threadIdx.x;       // k-octet 0..255
    const int k = o * 8;
    const float4 a = *(const float4*)(w + (size_t)e * HH + k);
    const float4 b = *(const float4*)(w + (size_t)e * HH + k + 4);
    short8 h, m, l;
    cvt3(a, b, h, m, l);

    const int eb  = e >> 5, lr = e & 31;
    const int s16 = o >> 1;          // 16-k-step index
    const int l5  = o & 1;           // k-octet within step
    const int lane = l5 * 32 + lr;
    short* dst = wsw + (((size_t)(eb * 128 + s16) * 3) * 64 + lane) * 8;
    *(short8*)(dst)           = h;   // p=0
    *(short8*)(dst + 64 * 8)  = m;   // p=1
    *(short8*)(dst + 128 * 8) = l;   // p=2
}

// ---------------- Main kernel ----------------
// 512 threads = 8 waves = eb(2) x kq(4). x is staged as RAW fp32 via
// global_load_lds (DMA, no VGPR round trip) with source-pre-swizzled
// addresses (linear LDS dest + XOR'd global unit + XOR'd ds_read: m173/#21).
// Stage for chunk c+1 is issued BEFORE compute of chunk c; one barrier per
// chunk drains it after compute has covered the latency (T3-minimal 2-phase).
// cvt3 of x happens in the compute waves. W limbs: fragment-ready from wsw.
__global__ __launch_bounds__(512, 4) void router_fused(
    const float* __restrict__ x,          // [NT, H] fp32
    const short* __restrict__ wsw,        // fragment-ready W limbs
    float* __restrict__ out_logits,
    float* __restrict__ out_wts,
    float* __restrict__ out_idx)
{
    // x tile: [buf][row r=0..31][unit u=0..31] of 16B units (4 floats).
    // LDS slot (r,u) holds logical unit (u ^ (r&7)) of row r. 32 KB total.
    __shared__ __align__(16) float xtile[2][MT * KC];
    float* slog = (float*)xtile;          // epilogue overlay (8.7 KB)

    const int t    = threadIdx.x;
    const int wv   = t >> 6;
    const int lane = t & 63;
    const int eb   = wv & 1;              // expert half (32 cols)
    const int kq   = wv >> 1;             // k-step slot within chunk (2 steps)
    const int l5   = lane >> 5;           // k-octet within 16-k step
    const int lr   = lane & 31;           // token row (A) / expert col (B)
    const int tok0 = blockIdx.x * MT;

    // staging geometry: round j covers slots t + j*512; slot = r*32 + u.
    const int r0 = t >> 5;                // row for j=0 (j=1: +16)
    const int u0s = t & 31;               // unit index (both rounds)
    const int wbase = (t & ~63) * 4;      // wave-uniform LDS float offset, j=0

    f32x16 accM = {0}, accS = {0};

    auto stage = [&](int c, int buf) {
#pragma unroll
        for (int j = 0; j < 2; ++j) {
            const int r = r0 + j * 16;
            const size_t goff = (size_t)(tok0 + r) * HH + c * KC
                              + ((u0s ^ (r & 7)) << 2);
            float* lp = &xtile[buf][wbase + j * 2048];   // + lane*16B by HW
            __builtin_amdgcn_global_load_lds(GLB(x + goff), LDS(lp), 16, 0, 0);
        }
    };

    auto chunk = [&](int c, int buf) {
#pragma unroll
        for (int st = 0; st < 2; ++st) {
            const int s    = kq * 2 + st;          // in-chunk k-step 0..7
            const int s16g = c * 8 + s;            // global k-step 0..127
            const short8* wp = (const short8*)wsw
                             + ((size_t)(eb * 128 + s16g) * 3) * 64 + lane;
            const short8 B0 = wp[0];
            const short8 B1 = wp[64];
            const short8 B2 = wp[128];
            // A fragment: row lr, logical units s*4 + l5*2 + {0,1}, swizzled
            const int v0 = s * 4 + l5 * 2;
            const float4 f0 = *(const float4*)
                &xtile[buf][lr * KC + ((v0      ^ (lr & 7)) << 2)];
            const float4 f1 = *(const float4*)
                &xtile[buf][lr * KC + (((v0 + 1) ^ (lr & 7)) << 2)];
            short8 Ah, Am, Al;
            cvt3(f0, f1, Ah, Am, Al);
            accM = __builtin_amdgcn_mfma_f32_32x32x16_bf16(Ah, B0, accM, 0, 0, 0);
            accS = __builtin_amdgcn_mfma_f32_32x32x16_bf16(Ah, B1, accS, 0, 0, 0);
            accS = __builtin_amdgcn_mfma_f32_32x32x16_bf16(Am, B0, accS, 0, 0, 0);
            accS = __builtin_amdgcn_mfma_f32_32x32x16_bf16(Ah, B2, accS, 0, 0, 0);
            accS = __builtin_amdgcn_mfma_f32_32x32x16_bf16(Al, B0, accS, 0, 0, 0);
            accS = __builtin_amdgcn_mfma_f32_32x32x16_bf16(Am, B1, accS, 0, 0, 0);
        }
    };

    // prologue: DMA chunk 0, drain, barrier
    stage(0, 0);
    __syncthreads();

#pragma unroll 1
    for (int c = 0; c < NCH; ++c) {
        if (c + 1 < NCH) stage(c + 1, (c + 1) & 1);  // fire-and-forget DMA
        chunk(c, c & 1);                             // compute covers latency
        __syncthreads();                             // drain vmcnt; swap bufs
    }
    // final barrier also guards the slog overlay below

    // ---- K-slot reduction into slog (R7-proven) ----
    // 32x32 C/D layout (m74/m101): col = lane&31, row = (r&3)+8*(r>>2)+4*(l>>5)
    const int col = eb * 32 + lr;
#pragma unroll 1
    for (int q = 0; q < 4; ++q) {
        if (kq == q) {
#pragma unroll
            for (int r = 0; r < 16; ++r) {
                const int row = (r & 3) + 8 * (r >> 2) + 4 * l5;
                const float val = accM[r] + accS[r];
                if (q == 0) slog[row * LS + col] = val;
                else        slog[row * LS + col] += val;
            }
        }
        __syncthreads();
    }

    // ---- coalesced logits write: 32 tokens x 64 experts, 512 threads ----
    {
        const int row = t >> 4;           // 0..31
        const int c4  = (t & 15) * 4;
        const float4 o0 = *(const float4*)&slog[row * LS + c4];
        *(float4*)(out_logits + (size_t)(tok0 + row) * EE + c4) = o0;
    }

    // ---- top-8 + softmax: one lane per token (harness-proven code) ----
    if (t < MT) {
        float tv[TOPK];
        int   ti[TOPK];
#pragma unroll
        for (int q = 0; q < TOPK; ++q) { tv[q] = -INFINITY; ti[q] = 0; }

        for (int e = 0; e < EE; ++e) {
            const float val = slog[t * LS + e];
            if (val > tv[TOPK - 1]) {
                tv[TOPK - 1] = val;
                ti[TOPK - 1] = e;
#pragma unroll
                for (int q = TOPK - 1; q > 0; --q) {
                    if (tv[q] > tv[q - 1]) {   // strict: lowest-index-first on ties
                        float fv = tv[q]; tv[q] = tv[q - 1]; tv[q - 1] = fv;
                        int   fi = ti[q]; ti[q] = ti[q - 1]; ti[q - 1] = fi;
                    }
                }
            }
        }

        const float m = tv[0];
        float ew[TOPK];
        float sum = 0.f;
#pragma unroll
        for (int q = 0; q < TOPK; ++q) { ew[q] = expf(tv[q] - m); sum += ew[q]; }
        const float inv = 1.f / sum;

        const size_t tok = (size_t)(tok0 + t);
        float4 w0, w1, i0, i1;
        w0.x = ew[0] * inv; w0.y = ew[1] * inv; w0.z = ew[2] * inv; w0.w = ew[3] * inv;
        w1.x = ew[4] * inv; w1.y = ew[5] * inv; w1.z = ew[6] * inv; w1.w = ew[7] * inv;
        i0.x = (float)ti[0]; i0.y = (float)ti[1]; i0.z = (float)ti[2]; i0.w = (float)ti[3];
        i1.x = (float)ti[4]; i1.y = (float)ti[5]; i1.z = (float)ti[6]; i1.w = (float)ti[7];
        *(float4*)(out_wts + tok * TOPK)     = w0;
        *(float4*)(out_wts + tok * TOPK + 4) = w1;
        *(float4*)(out_idx + tok * TOPK)     = i0;
        *(float4*)(out_idx + tok * TOPK + 4) = i1;
    }
}

extern "C" void kernel_launch(void* const* d_in, const int* in_sizes, int n_in,
                              void* d_out, int out_size, void* d_ws, size_t ws_size,
                              hipStream_t stream) {
    const float* x = (const float*)d_in[0];   // hidden_states [4,4096,2048] fp32
    const float* w = (const float*)d_in[1];   // gate_w [64,2048] fp32
    float* out        = (float*)d_out;
    float* out_logits = out;                               // 16384*64
    float* out_wts    = out + (size_t)NT * EE;             // 16384*8
    float* out_idx    = out_wts + (size_t)NT * TOPK;       // 16384*8
    short* wsw = (short*)d_ws;                             // 768 KB limb planes

    hipLaunchKernelGGL(wsplit, dim3(EE), dim3(256), 0, stream, w, wsw);
    hipLaunchKernelGGL(router_fused, dim3(NT / MT), dim3(512), 0, stream,
                       x, wsw, out_logits, out_wts, out_idx);
}